// Round 12
// baseline (242.329 us; speedup 1.0000x reference)
//
#include <hip/hip_runtime.h>
#include <hip/hip_bf16.h>
#include <cstdint>
#include <cstddef>

#define NUM_CLASS 1000
#define NPAD      1024
#define LOW_DIM   128
#define B_UPD     1024
#define B_SIM     65536

typedef short bf16x8 __attribute__((ext_vector_type(8)));
typedef float f32x4  __attribute__((ext_vector_type(4)));

__device__ __forceinline__ unsigned short f2bf(float f) {
  union { float f; unsigned u; } a; a.f = f;
  unsigned u = a.u;
  return (unsigned short)((u + 0x7fffu + ((u >> 16) & 1u)) >> 16);  // RNE
}

// ---------- kernel 1: per-class EMA (ballot scan) + L2 norm -> fragment-swizzled bf16 ----------
// Updates to different labels commute, so per-class in-order processing
// reproduces the reference lax.scan exactly.
// Output layout = MFMA B-operand fragment order (lane l: col=l&15, k=(l>>4)*8+e):
//   slot[((g*4 + kk)*64 + l) * 8 + e]  (ushort units)
//   holds logical B[row = g*16 + (l&15)][k = kk*32 + (l>>4)*8 + e]
__global__ void proto_update_kernel(const float* __restrict__ pred_feat,
                                    const int*   __restrict__ labels,
                                    const float* __restrict__ protos_in,
                                    unsigned short* __restrict__ protos_sw) {
  int c = blockIdx.x;    // 0..1023
  int d = threadIdx.x;   // 0..127
  float p = 0.0f;
  if (c < NUM_CLASS) {
    p = protos_in[c * LOW_DIM + d];
    #pragma unroll 4
    for (int k = 0; k < B_UPD / 64; ++k) {
      int lab = labels[k * 64 + (d & 63)];
      unsigned long long m = __ballot(lab == c);   // wave-uniform
      while (m) {
        int b = __builtin_ctzll(m);
        m &= (m - 1);
        p = 0.99f * p + 0.01f * pred_feat[(size_t)(k * 64 + b) * LOW_DIM + d];
      }
    }
  }
  float sq = p * p;
  #pragma unroll
  for (int o = 1; o < 64; o <<= 1) sq += __shfl_xor(sq, o, 64);
  __shared__ float wsum[2];
  if ((d & 63) == 0) wsum[d >> 6] = sq;
  __syncthreads();
  float total = wsum[0] + wsum[1];
  unsigned short v = f2bf(p / fmaxf(sqrtf(total), 1e-12f));  // c>=1000 -> 0
  int g = c >> 4, r = c & 15, kk = d >> 5, j = (d >> 3) & 3, e = d & 7;
  protos_sw[(size_t)((g * 4 + kk) * 64 + j * 16 + r) * 8 + e] = v;
}

// ---------- kernel 2: C[65536,1000] = A(f32->bf16) @ B^T, 4-tile pipeline ----------
// R6 per-tile structure (BM=32, TPB=512, 8 waves, acc[2][8], mfma(feat,proto),
// 512B-chunk LDS-transpose epilogue) in a 4-tile loop with NON-DRAINING
// barriers (raw s_barrier + lgkmcnt(0) only, never vmcnt(0)): tile i's
// C-stores stay in flight and drain across tile i+1's K-loop, making the
// write stream continuous instead of phase-aligned bursts.
// R11 NaN root cause fixed here: A-tile and epilogue LDS are now DISJOINT
// (A at [0,8K), epilogue at [8K,8K+67584)). R6's union was only safe with a
// barrier between K-loop and epilogue; the pipeline has no such barrier, so
// a fast wave's epilogue ds_writes were corrupting the A-tile under slower
// waves' K-loop reads. LDS total 75776 B -> still 2 blocks/CU.
#define BM    32
#define TILES 4
#define TPB2  512
#define CPAD  132                // epilogue f32 LDS row stride (128+4)
#define EPW   (16 * CPAD)        // floats per wave epilogue region (8448 B)

__global__ __launch_bounds__(TPB2, 4)
void gemm_sim_kernel(const float* __restrict__ A,
                     const unsigned short* __restrict__ Bsw,
                     float* __restrict__ C) {
  __shared__ unsigned char smem[8192 + 8 * EPW * 4];   // A-tile | 8 epilogue regions
  int t    = threadIdx.x;
  int lane = t & 63;
  int w    = t >> 6;
  int lr   = lane & 15;
  int lkb  = (lane >> 4) * 16;
  int arow = t >> 4, ac8 = t & 15;             // this thread's A-stage slot
  float* myT = reinterpret_cast<float*>(smem + 8192) + w * EPW;

  // ---- prologue: stage tile 0's A (32 rows x 128 f32 -> bf16, XOR-swizzled) ----
  {
    int m0 = blockIdx.x * (TILES * BM);
    const float4* s = reinterpret_cast<const float4*>(A + (size_t)(m0 + arow) * LOW_DIM + ac8 * 8);
    float4 v0 = s[0], v1 = s[1];
    uint4 q;
    q.x = f2bf(v0.x) | ((unsigned)f2bf(v0.y) << 16);
    q.y = f2bf(v0.z) | ((unsigned)f2bf(v0.w) << 16);
    q.z = f2bf(v1.x) | ((unsigned)f2bf(v1.y) << 16);
    q.w = f2bf(v1.z) | ((unsigned)f2bf(v1.w) << 16);
    *reinterpret_cast<uint4*>(smem + arow * 256 + ((ac8 * 16) ^ ((arow & 7) << 4))) = q;
  }
  __syncthreads();   // prologue only: nothing in flight worth preserving

  for (int tile = 0; tile < TILES; ++tile) {
    int m0 = blockIdx.x * (TILES * BM) + tile * BM;

    // ---- K-loop (reads swizzled A tile in smem; B from L2) ----
    f32x4 acc[2][8];
    #pragma unroll
    for (int m = 0; m < 2; ++m)
      #pragma unroll
      for (int n = 0; n < 8; ++n)
        acc[m][n] = (f32x4){0.f, 0.f, 0.f, 0.f};

    #pragma unroll
    for (int kk = 0; kk < 4; ++kk) {           // K = 4 x 32
      int kb = kk * 64 + lkb;
      bf16x8 af[2];
      #pragma unroll
      for (int m = 0; m < 2; ++m) {
        int row = m * 16 + lr;
        af[m] = *reinterpret_cast<const bf16x8*>(smem + row * 256 + (kb ^ ((row & 7) << 4)));
      }
      #pragma unroll
      for (int n = 0; n < 8; ++n) {
        int g = w * 8 + n;                     // 16-class group
        bf16x8 bf = *reinterpret_cast<const bf16x8*>(
            Bsw + ((size_t)(g * 4 + kk) * 64 + lane) * 8);   // coalesced 1KB/wave
        #pragma unroll
        for (int m = 0; m < 2; ++m)
          acc[m][n] = __builtin_amdgcn_mfma_f32_16x16x32_bf16(af[m], bf, acc[m][n], 0, 0, 0);
      }
    }

    // ---- issue next tile's A loads FIRST (before C stores -> the staging
    //      wait is vmcnt(16), the 16 stores stay in flight) ----
    float4 nv0, nv1;
    bool have_next = (tile + 1 < TILES);
    if (have_next) {
      const float4* s = reinterpret_cast<const float4*>(
          A + (size_t)(m0 + BM + arow) * LOW_DIM + ac8 * 8);
      nv0 = s[0]; nv1 = s[1];
    }

    // ---- epilogue: per-wave LDS transpose + 512B-chunk stores (R6-proven) ----
    // myT is wave-private and disjoint from the A-tile: no cross-wave hazard.
    #pragma unroll
    for (int m = 0; m < 2; ++m) {
      int rbase = (lane >> 4) * 4;
      #pragma unroll
      for (int n = 0; n < 8; ++n) {
        #pragma unroll
        for (int r = 0; r < 4; ++r)
          myT[(rbase + r) * CPAD + n * 16 + lr] = acc[m][n][r];
      }
      #pragma unroll
      for (int it = 0; it < 8; ++it) {
        int idx = it * 64 + lane;
        int row = idx >> 5, c4 = idx & 31;
        f32x4 v = *reinterpret_cast<const f32x4*>(myT + row * CPAD + c4 * 4);
        int col = w * 128 + c4 * 4;
        if (col < NUM_CLASS) {   // only wave 7 tail masked; 1000 % 4 == 0
          *reinterpret_cast<f32x4*>(C + (size_t)(m0 + m * 16 + row) * NUM_CLASS + col) = v;
        }
      }
    }

    if (have_next) {
      // barrier 1: every wave is past its K-loop (and epilogue) -> safe to
      // overwrite the A-tile. Raw s_barrier: vmcnt NOT drained, C-stores
      // continue in background.
      __builtin_amdgcn_sched_barrier(0);
      __builtin_amdgcn_s_barrier();
      __builtin_amdgcn_sched_barrier(0);

      // stage next A tile (needs only the 2 A-loads: s_waitcnt vmcnt(16))
      uint4 q;
      q.x = f2bf(nv0.x) | ((unsigned)f2bf(nv0.y) << 16);
      q.y = f2bf(nv0.z) | ((unsigned)f2bf(nv0.w) << 16);
      q.z = f2bf(nv1.x) | ((unsigned)f2bf(nv1.y) << 16);
      q.w = f2bf(nv1.z) | ((unsigned)f2bf(nv1.w) << 16);
      *reinterpret_cast<uint4*>(smem + arow * 256 + ((ac8 * 16) ^ ((arow & 7) << 4))) = q;

      // barrier 2: staging ds_writes visible to all waves; drain LDS only
      // (lgkmcnt), never vmcnt (rule #18: sched_barrier after asm waitcnt).
      asm volatile("s_waitcnt lgkmcnt(0)" ::: "memory");
      __builtin_amdgcn_sched_barrier(0);
      __builtin_amdgcn_s_barrier();
      __builtin_amdgcn_sched_barrier(0);
    }
  }
}

extern "C" void kernel_launch(void* const* d_in, const int* in_sizes, int n_in,
                              void* d_out, int out_size, void* d_ws, size_t ws_size,
                              hipStream_t stream) {
  const float* pred_feat = (const float*)d_in[0];   // [1024,128]
  const int*   labels    = (const int*)d_in[1];     // [1024]
  const float* protos    = (const float*)d_in[2];   // [1000,128]
  const float* feat      = (const float*)d_in[3];   // [65536,128]
  float* out = (float*)d_out;                       // [65536,1000]

  unsigned short* protos_sw = (unsigned short*)d_ws;  // 256 KB fragment-swizzled

  proto_update_kernel<<<NPAD, 128, 0, stream>>>(pred_feat, labels, protos, protos_sw);
  gemm_sim_kernel<<<B_SIM / (BM * TILES), TPB2, 0, stream>>>(feat, protos_sw, out);
}